// Round 9
// baseline (322.823 us; speedup 1.0000x reference)
//
#include <hip/hip_runtime.h>
#include <hip/hip_cooperative_groups.h>
#include <hip/hip_bf16.h>

namespace cg = cooperative_groups;

#define NROWS 8192
#define KDIM  512
#define NT    64                 // 8192/128 tiles per dim
#define NBLK  (NT*(NT+1)/2)      // upper-triangle tile pairs = 2080
#define GRID  512                // persistent blocks (2/CU co-resident)
#define SCL1  0x7F7F7F7F         // E8M0 scale bytes = 2^0 = 1.0
#define STRIP_BYTES (32 * KDIM)  // 16384 B per 32-row strip
#define C2    0.0144269504f      // log2(e)/100

typedef __attribute__((ext_vector_type(16))) float f32x16;
typedef __attribute__((ext_vector_type(4))) int i32x4;
typedef __attribute__((ext_vector_type(8))) int i32x8;

__device__ __forceinline__ i32x8 mk_op(i32x4 lo, i32x4 hi) {
    i32x8 r;
    r[0] = lo[0]; r[1] = lo[1]; r[2] = lo[2]; r[3] = lo[3];
    r[4] = hi[0]; r[5] = hi[1]; r[6] = hi[2]; r[7] = hi[3];
    return r;
}

// ONE cooperative kernel: phase 1 converts z -> fp8 operand-order zb2
// (layout HW-verified rounds 4-8) + nq; grid.sync; phase 2: persistent
// blocks each process 4-5 Gram tiles, per-thread accumulation across
// tiles; grid.sync; block 0 reduces 512 partials -> log -> out.
__global__ __launch_bounds__(256, 2) void fused_kernel(const float* __restrict__ z,
                                                       unsigned char* __restrict__ zb2,
                                                       float* __restrict__ nq,
                                                       float* __restrict__ part,
                                                       float* __restrict__ out) {
    cg::grid_group gg = cg::this_grid();
    __shared__ float wsum[4];

    int tid = threadIdx.x;
    int wave = tid >> 6, lane = tid & 63;

    // ---------------- phase 1: fp8 convert + nq (16 rows/block) ----------------
#pragma unroll
    for (int rr = 0; rr < 4; ++rr) {
        int row = blockIdx.x * 16 + wave * 4 + rr;
        const float* zr = z + (size_t)row * KDIM + lane * 8;
        float4 v0 = *(const float4*)zr;
        float4 v1 = *(const float4*)(zr + 4);
        float vals[8] = {v0.x, v0.y, v0.z, v0.w, v1.x, v1.y, v1.z, v1.w};
        float s = 0.f;
#pragma unroll
        for (int i = 0; i < 8; ++i) s += vals[i] * vals[i];
        int lo = __builtin_amdgcn_cvt_pk_fp8_f32(vals[0], vals[1], 0, false);
        lo     = __builtin_amdgcn_cvt_pk_fp8_f32(vals[2], vals[3], lo, true);
        int hi = __builtin_amdgcn_cvt_pk_fp8_f32(vals[4], vals[5], 0, false);
        hi     = __builtin_amdgcn_cvt_pk_fp8_f32(vals[6], vals[7], hi, true);
        int2 pk; pk.x = lo; pk.y = hi;
        int strip = row >> 5, lr = row & 31;
        size_t addr = (size_t)strip * STRIP_BYTES + (lane >> 3) * 2048 +
                      ((lane >> 1) & 3) * 512 + lr * 16 + (lane & 1) * 8;
        *(int2*)(zb2 + addr) = pk;
#pragma unroll
        for (int off = 32; off; off >>= 1) s += __shfl_down(s, off);
        if (lane == 0) nq[row] = -C2 * s;
    }

    __threadfence();
    gg.sync();

    // ---------------- phase 2: persistent Gram tiles ----------------
    int ln31 = lane & 31, kh = lane >> 5;
    int wm = wave >> 1, wn = wave & 1;
    int laneOff = kh * 1024 + ln31 * 16;

    float local = 0.f;
    for (int t = blockIdx.x; t < NBLK; t += GRID) {
        int rem = t, bi = 0;
        while (rem >= NT - bi) { rem -= NT - bi; ++bi; }
        int bj = bi + rem;
        int rot = t & 7;

        const unsigned char* pA0 = zb2 + (size_t)(bi * 4 + wm * 2) * STRIP_BYTES + laneOff;
        const unsigned char* pA1 = pA0 + STRIP_BYTES;
        const unsigned char* pB0 = zb2 + (size_t)(bj * 4 + wn * 2) * STRIP_BYTES + laneOff;
        const unsigned char* pB1 = pB0 + STRIP_BYTES;

        f32x16 accf[2][2];
#pragma unroll
        for (int mi = 0; mi < 2; ++mi)
#pragma unroll
            for (int ni = 0; ni < 2; ++ni)
#pragma unroll
                for (int r = 0; r < 16; ++r) accf[mi][ni][r] = 0.f;

        // 4 batches of 2 ksteps: 16 loads in flight, then 8 MFMA
#pragma unroll
        for (int h = 0; h < 4; ++h) {
            i32x4 Av[8], Bv[8];
#pragma unroll
            for (int ks = 0; ks < 2; ++ks) {
                int off = ((h * 2 + ks + rot) & 7) * 2048;   // rotated k-slice
                Av[ks * 4 + 0] = *(const i32x4*)(pA0 + off);
                Av[ks * 4 + 1] = *(const i32x4*)(pA0 + off + 512);
                Av[ks * 4 + 2] = *(const i32x4*)(pA1 + off);
                Av[ks * 4 + 3] = *(const i32x4*)(pA1 + off + 512);
                Bv[ks * 4 + 0] = *(const i32x4*)(pB0 + off);
                Bv[ks * 4 + 1] = *(const i32x4*)(pB0 + off + 512);
                Bv[ks * 4 + 2] = *(const i32x4*)(pB1 + off);
                Bv[ks * 4 + 3] = *(const i32x4*)(pB1 + off + 512);
            }
#pragma unroll
            for (int ks = 0; ks < 2; ++ks) {
                i32x8 a0 = mk_op(Av[ks * 4 + 0], Av[ks * 4 + 1]);
                i32x8 a1 = mk_op(Av[ks * 4 + 2], Av[ks * 4 + 3]);
                i32x8 b0 = mk_op(Bv[ks * 4 + 0], Bv[ks * 4 + 1]);
                i32x8 b1 = mk_op(Bv[ks * 4 + 2], Bv[ks * 4 + 3]);
                accf[0][0] = __builtin_amdgcn_mfma_scale_f32_32x32x64_f8f6f4(a0, b0, accf[0][0], 0, 0, 0, SCL1, 0, SCL1);
                accf[0][1] = __builtin_amdgcn_mfma_scale_f32_32x32x64_f8f6f4(a0, b1, accf[0][1], 0, 0, 0, SCL1, 0, SCL1);
                accf[1][0] = __builtin_amdgcn_mfma_scale_f32_32x32x64_f8f6f4(a1, b0, accf[1][0], 0, 0, 0, SCL1, 0, SCL1);
                accf[1][1] = __builtin_amdgcn_mfma_scale_f32_32x32x64_f8f6f4(a1, b1, accf[1][1], 0, 0, 0, SCL1, 0, SCL1);
            }
        }

        // epilogue: exp2( min( s*2C2 + nq_i + nq_j, 0 ) )
        int rowBase = bi * 128 + wm * 64;
        int colBase = bj * 128 + wn * 64;
        float nqj[2] = { nq[colBase + ln31], nq[colBase + 32 + ln31] };

        if (bi != bj) {
#pragma unroll
            for (int mi = 0; mi < 2; ++mi) {
#pragma unroll
                for (int reg = 0; reg < 16; ++reg) {
                    int rowf = (reg & 3) + 8 * (reg >> 2) + 4 * kh;
                    float nqi = nq[rowBase + mi * 32 + rowf];
#pragma unroll
                    for (int ni = 0; ni < 2; ++ni) {
                        float arg = fmaf(accf[mi][ni][reg], 2.f * C2, nqi + nqj[ni]);
                        local += __builtin_exp2f(fminf(arg, 0.f));
                    }
                }
            }
        } else {
#pragma unroll
            for (int mi = 0; mi < 2; ++mi) {
#pragma unroll
                for (int reg = 0; reg < 16; ++reg) {
                    int rowf = (reg & 3) + 8 * (reg >> 2) + 4 * kh;
                    int gi = rowBase + mi * 32 + rowf;
                    float nqi = nq[gi];
#pragma unroll
                    for (int ni = 0; ni < 2; ++ni) {
                        int gj = colBase + ni * 32 + ln31;
                        float arg = fmaf(accf[mi][ni][reg], 2.f * C2, nqi + nqj[ni]);
                        float e = __builtin_exp2f(fminf(arg, 0.f));
                        local += (gi < gj) ? e : 0.f;
                    }
                }
            }
        }
    }

    // block reduction -> part[blockIdx.x] (plain store, no atomics)
#pragma unroll
    for (int off = 32; off; off >>= 1) local += __shfl_down(local, off);
    if (lane == 0) wsum[wave] = local;
    __syncthreads();
    if (tid == 0) part[blockIdx.x] = wsum[0] + wsum[1] + wsum[2] + wsum[3];

    __threadfence();
    gg.sync();

    // ---------------- phase 3: block 0 final reduce + log ----------------
    if (blockIdx.x == 0) {
        float s = 0.f;
        for (int i = tid; i < GRID; i += 256) s += part[i];
#pragma unroll
        for (int off = 32; off; off >>= 1) s += __shfl_down(s, off);
        __syncthreads();               // wsum reuse safety
        if (lane == 0) wsum[wave] = s;
        __syncthreads();
        if (tid == 0) {
            float total = 2.f * (wsum[0] + wsum[1] + wsum[2] + wsum[3]);
            out[0] = logf(total / ((float)NROWS * (float)(NROWS - 1)));
        }
    }
}

extern "C" void kernel_launch(void* const* d_in, const int* in_sizes, int n_in,
                              void* d_out, int out_size, void* d_ws, size_t ws_size,
                              hipStream_t stream) {
    const float* z = (const float*)d_in[0];
    float* out = (float*)d_out;
    unsigned char* zb2 = (unsigned char*)d_ws;                    // 4 MB fp8, operand order
    float* nq = (float*)((char*)d_ws + (size_t)NROWS * KDIM);     // 32 KB
    float* part = nq + NROWS;                                     // 512 floats

    void* args[] = { (void*)&z, (void*)&zb2, (void*)&nq, (void*)&part, (void*)&out };
    hipLaunchCooperativeKernel((const void*)fused_kernel, dim3(GRID), dim3(256),
                               args, 0, stream);
}

// Round 10
// 110.774 us; speedup vs baseline: 2.9142x; 2.9142x over previous
//
#include <hip/hip_runtime.h>
#include <hip/hip_bf16.h>

#define NROWS 8192
#define KDIM  512
#define NT2   32                 // 8192/256 tiles per dim
#define NBLK2 (NT2*(NT2+1)/2)    // 528 upper-triangle tile pairs
#define SCL1  0x7F7F7F7F         // E8M0 scale bytes = 2^0 = 1.0
#define STRIP_BYTES (32 * KDIM)  // 16384 B per 32-row strip
#define C2    0.0144269504f      // log2(e)/100

typedef __attribute__((ext_vector_type(16))) float f32x16;
typedef __attribute__((ext_vector_type(4))) int i32x4;
typedef __attribute__((ext_vector_type(8))) int i32x8;

__device__ __forceinline__ i32x8 mk_op(i32x4 lo, i32x4 hi) {
    i32x8 r;
    r[0] = lo[0]; r[1] = lo[1]; r[2] = lo[2]; r[3] = lo[3];
    r[4] = hi[0]; r[5] = hi[1]; r[6] = hi[2]; r[7] = hi[3];
    return r;
}

// z (fp32) -> fp8 e4m3 in MFMA-operand order (HW-verified rounds 4-9):
//   zb2 addr = strip*16384 + kstep*2048 + seg*512 + (row&31)*16 + (k&15)
// nq[i] = -log2e/100 * ||z_i||^2.
__global__ __launch_bounds__(256) void prep_kernel(const float* __restrict__ z,
                                                   unsigned char* __restrict__ zb2,
                                                   float* __restrict__ nq) {
    int wave = threadIdx.x >> 6, lane = threadIdx.x & 63;
    int row = blockIdx.x * 4 + wave;
    const float* zr = z + (size_t)row * KDIM + lane * 8;
    float4 v0 = *(const float4*)zr;
    float4 v1 = *(const float4*)(zr + 4);
    float vals[8] = {v0.x, v0.y, v0.z, v0.w, v1.x, v1.y, v1.z, v1.w};
    float s = 0.f;
#pragma unroll
    for (int i = 0; i < 8; ++i) s += vals[i] * vals[i];
    int lo = __builtin_amdgcn_cvt_pk_fp8_f32(vals[0], vals[1], 0, false);
    lo     = __builtin_amdgcn_cvt_pk_fp8_f32(vals[2], vals[3], lo, true);
    int hi = __builtin_amdgcn_cvt_pk_fp8_f32(vals[4], vals[5], 0, false);
    hi     = __builtin_amdgcn_cvt_pk_fp8_f32(vals[6], vals[7], hi, true);
    int2 pk; pk.x = lo; pk.y = hi;
    int strip = row >> 5, lr = row & 31;
    size_t addr = (size_t)strip * STRIP_BYTES + (lane >> 3) * 2048 +
                  ((lane >> 1) & 3) * 512 + lr * 16 + (lane & 1) * 8;
    *(int2*)(zb2 + addr) = pk;
#pragma unroll
    for (int off = 32; off; off >>= 1) s += __shfl_down(s, off);
    if (lane == 0) nq[row] = -C2 * s;
}

// 256x256 Gram tile per block; each wave computes a 128x128 quadrant
// (16 x 32x32 MFMA tiles, 256 acc regs). Halves the bytes-per-MAC through
// the per-CU vector-memory return port vs the 64x64-per-wave design.
// No LDS staging, no barriers, no atomics.
__global__ __launch_bounds__(256, 1) void gram_kernel(const unsigned char* __restrict__ zb2,
                                                      const float* __restrict__ nq,
                                                      float* __restrict__ part) {
    __shared__ float wsum[4];

    int tid = threadIdx.x;
    int wave = tid >> 6, lane = tid & 63;
    int ln31 = lane & 31, kh = lane >> 5;
    int wm = wave >> 1, wn = wave & 1;

    // linear block id -> (bi, bj), bi <= bj over NT2=32
    int rem = blockIdx.x, bi = 0;
    while (rem >= NT2 - bi) { rem -= NT2 - bi; ++bi; }
    int bj = bi + rem;
    int rot = blockIdx.x & 7;

    float local = 0.f;
    bool skip = (bi == bj) && (wm > wn);   // wave-uniform: strictly-lower quadrant of diag tile

    if (!skip) {
        int laneOff = kh * 1024 + ln31 * 16;
        const unsigned char* pA[4];
        const unsigned char* pB[4];
#pragma unroll
        for (int s = 0; s < 4; ++s) {
            pA[s] = zb2 + (size_t)(bi * 8 + wm * 4 + s) * STRIP_BYTES + laneOff;
            pB[s] = zb2 + (size_t)(bj * 8 + wn * 4 + s) * STRIP_BYTES + laneOff;
        }

        f32x16 accf[4][4];
#pragma unroll
        for (int mi = 0; mi < 4; ++mi)
#pragma unroll
            for (int ni = 0; ni < 4; ++ni)
#pragma unroll
                for (int r = 0; r < 16; ++r) accf[mi][ni][r] = 0.f;

        for (int ks = 0; ks < 8; ++ks) {
            int off = ((ks + rot) & 7) * 2048;   // rotated k-slice (decorrelates L2 bursts)
            i32x8 a[4], b[4];
#pragma unroll
            for (int s = 0; s < 4; ++s) {
                a[s] = mk_op(*(const i32x4*)(pA[s] + off), *(const i32x4*)(pA[s] + off + 512));
                b[s] = mk_op(*(const i32x4*)(pB[s] + off), *(const i32x4*)(pB[s] + off + 512));
            }
#pragma unroll
            for (int mi = 0; mi < 4; ++mi)
#pragma unroll
                for (int ni = 0; ni < 4; ++ni)
                    accf[mi][ni] = __builtin_amdgcn_mfma_scale_f32_32x32x64_f8f6f4(
                        a[mi], b[ni], accf[mi][ni], 0, 0, 0, SCL1, 0, SCL1);
        }

        // ---- fused epilogue: exp2( min( s*2C2 + nq_i + nq_j, 0 ) ) ----
        int rowBase = bi * 256 + wm * 128;
        int colBase = bj * 256 + wn * 128;
        float nqj[4];
#pragma unroll
        for (int ni = 0; ni < 4; ++ni) nqj[ni] = nq[colBase + ni * 32 + ln31];

        bool masked = (bi == bj) && (wm == wn);  // wave-uniform
        if (!masked) {
#pragma unroll
            for (int mi = 0; mi < 4; ++mi) {
#pragma unroll
                for (int reg = 0; reg < 16; ++reg) {
                    int rowf = (reg & 3) + 8 * (reg >> 2) + 4 * kh;
                    float nqi = nq[rowBase + mi * 32 + rowf];
#pragma unroll
                    for (int ni = 0; ni < 4; ++ni) {
                        float arg = fmaf(accf[mi][ni][reg], 2.f * C2, nqi + nqj[ni]);
                        local += __builtin_exp2f(fminf(arg, 0.f));
                    }
                }
            }
        } else {
#pragma unroll
            for (int mi = 0; mi < 4; ++mi) {
#pragma unroll
                for (int reg = 0; reg < 16; ++reg) {
                    int rowf = (reg & 3) + 8 * (reg >> 2) + 4 * kh;
                    int gi = rowBase + mi * 32 + rowf;
                    float nqi = nq[gi];
#pragma unroll
                    for (int ni = 0; ni < 4; ++ni) {
                        int gj = colBase + ni * 32 + ln31;
                        float arg = fmaf(accf[mi][ni][reg], 2.f * C2, nqi + nqj[ni]);
                        float e = __builtin_exp2f(fminf(arg, 0.f));
                        local += (gi < gj) ? e : 0.f;
                    }
                }
            }
        }
    }

#pragma unroll
    for (int off = 32; off; off >>= 1) local += __shfl_down(local, off);
    if (lane == 0) wsum[wave] = local;
    __syncthreads();
    if (tid == 0) part[blockIdx.x] = wsum[0] + wsum[1] + wsum[2] + wsum[3];  // plain store
}

// Single small block: sum the 528 partials, take the log.
__global__ __launch_bounds__(256) void reduce_kernel(const float* __restrict__ part,
                                                     float* __restrict__ out) {
    int tid = threadIdx.x;
    int wave = tid >> 6, lane = tid & 63;
    float s = 0.f;
    for (int i = tid; i < NBLK2; i += 256) s += part[i];
#pragma unroll
    for (int off = 32; off; off >>= 1) s += __shfl_down(s, off);
    __shared__ float w[4];
    if (lane == 0) w[wave] = s;
    __syncthreads();
    if (tid == 0) {
        float total = 2.f * (w[0] + w[1] + w[2] + w[3]);
        out[0] = logf(total / ((float)NROWS * (float)(NROWS - 1)));
    }
}

extern "C" void kernel_launch(void* const* d_in, const int* in_sizes, int n_in,
                              void* d_out, int out_size, void* d_ws, size_t ws_size,
                              hipStream_t stream) {
    const float* z = (const float*)d_in[0];
    float* out = (float*)d_out;
    unsigned char* zb2 = (unsigned char*)d_ws;                    // 4 MB fp8, operand order
    float* nq = (float*)((char*)d_ws + (size_t)NROWS * KDIM);     // 32 KB
    float* part = nq + NROWS;                                     // 528 floats

    prep_kernel<<<NROWS / 4, 256, 0, stream>>>(z, zb2, nq);
    gram_kernel<<<NBLK2, 256, 0, stream>>>(zb2, nq, part);
    reduce_kernel<<<1, 256, 0, stream>>>(part, out);
}

// Round 11
// 93.063 us; speedup vs baseline: 3.4689x; 1.1903x over previous
//
#include <hip/hip_runtime.h>
#include <hip/hip_bf16.h>

#define NROWS 8192
#define KDIM  512
#define NT    64                 // 8192/128 tiles per dim
#define NBLK  (NT*(NT+1)/2)      // upper-triangle tile pairs = 2080
#define SCL1  0x7F7F7F7F         // E8M0 scale bytes = 2^0 = 1.0
#define STRIP_BYTES (32 * KDIM)  // 16384 B per 32-row strip
#define C2    0.0144269504f      // log2(e)/100

typedef __attribute__((ext_vector_type(16))) float f32x16;
typedef __attribute__((ext_vector_type(4))) int i32x4;
typedef __attribute__((ext_vector_type(8))) int i32x8;

__device__ __forceinline__ i32x8 mk_op(i32x4 lo, i32x4 hi) {
    i32x8 r;
    r[0] = lo[0]; r[1] = lo[1]; r[2] = lo[2]; r[3] = lo[3];
    r[4] = hi[0]; r[5] = hi[1]; r[6] = hi[2]; r[7] = hi[3];
    return r;
}

// z (fp32) -> fp8 e4m3 in MFMA-operand order (HW-verified rounds 4-10):
//   zb2 addr = strip*16384 + kstep*2048 + seg*512 + (row&31)*16 + (k&15)
// nq[i] = -log2e/100 * ||z_i||^2.
__global__ __launch_bounds__(256) void prep_kernel(const float* __restrict__ z,
                                                   unsigned char* __restrict__ zb2,
                                                   float* __restrict__ nq) {
    int wave = threadIdx.x >> 6, lane = threadIdx.x & 63;
    int row = blockIdx.x * 4 + wave;
    const float* zr = z + (size_t)row * KDIM + lane * 8;
    float4 v0 = *(const float4*)zr;
    float4 v1 = *(const float4*)(zr + 4);
    float vals[8] = {v0.x, v0.y, v0.z, v0.w, v1.x, v1.y, v1.z, v1.w};
    float s = 0.f;
#pragma unroll
    for (int i = 0; i < 8; ++i) s += vals[i] * vals[i];
    int lo = __builtin_amdgcn_cvt_pk_fp8_f32(vals[0], vals[1], 0, false);
    lo     = __builtin_amdgcn_cvt_pk_fp8_f32(vals[2], vals[3], lo, true);
    int hi = __builtin_amdgcn_cvt_pk_fp8_f32(vals[4], vals[5], 0, false);
    hi     = __builtin_amdgcn_cvt_pk_fp8_f32(vals[6], vals[7], hi, true);
    int2 pk; pk.x = lo; pk.y = hi;
    int strip = row >> 5, lr = row & 31;
    size_t addr = (size_t)strip * STRIP_BYTES + (lane >> 3) * 2048 +
                  ((lane >> 1) & 3) * 512 + lr * 16 + (lane & 1) * 8;
    *(int2*)(zb2 + addr) = pk;
#pragma unroll
    for (int off = 32; off; off >>= 1) s += __shfl_down(s, off);
    if (lane == 0) nq[row] = -C2 * s;
}

// 128x128 Gram tile per block, 64x64 per wave (2x2 32x32 MFMA). Low VGPR
// (rolled K-loop, no operand batching) to fit 3 blocks/CU = 12 waves/CU:
// TLP, not ILP, hides L2 latency (r10 showed 4 waves/CU is latency-bound).
// No LDS staging, no barriers, no atomics.
__global__ __launch_bounds__(256, 3) void gram_kernel(const unsigned char* __restrict__ zb2,
                                                      const float* __restrict__ nq,
                                                      float* __restrict__ part) {
    __shared__ float wsum[4];

    int tid = threadIdx.x;
    int wave = tid >> 6, lane = tid & 63;
    int ln31 = lane & 31, kh = lane >> 5;
    int wm = wave >> 1, wn = wave & 1;

    // linear block id -> (bi, bj), bi <= bj
    int rem = blockIdx.x, bi = 0;
    while (rem >= NT - bi) { rem -= NT - bi; ++bi; }
    int bj = bi + rem;
    int rot = blockIdx.x & 7;

    int laneOff = kh * 1024 + ln31 * 16;
    const unsigned char* pA0 = zb2 + (size_t)(bi * 4 + wm * 2) * STRIP_BYTES + laneOff;
    const unsigned char* pA1 = pA0 + STRIP_BYTES;
    const unsigned char* pB0 = zb2 + (size_t)(bj * 4 + wn * 2) * STRIP_BYTES + laneOff;
    const unsigned char* pB1 = pB0 + STRIP_BYTES;

    f32x16 accf[2][2];
#pragma unroll
    for (int mi = 0; mi < 2; ++mi)
#pragma unroll
        for (int ni = 0; ni < 2; ++ni)
#pragma unroll
            for (int r = 0; r < 16; ++r) accf[mi][ni][r] = 0.f;

#pragma unroll
    for (int ks = 0; ks < 8; ++ks) {
        int off = ((ks + rot) & 7) * 2048;   // rotated k-slice (decorrelates L2 bursts)
        i32x8 a0 = mk_op(*(const i32x4*)(pA0 + off), *(const i32x4*)(pA0 + off + 512));
        i32x8 a1 = mk_op(*(const i32x4*)(pA1 + off), *(const i32x4*)(pA1 + off + 512));
        i32x8 b0 = mk_op(*(const i32x4*)(pB0 + off), *(const i32x4*)(pB0 + off + 512));
        i32x8 b1 = mk_op(*(const i32x4*)(pB1 + off), *(const i32x4*)(pB1 + off + 512));
        accf[0][0] = __builtin_amdgcn_mfma_scale_f32_32x32x64_f8f6f4(a0, b0, accf[0][0], 0, 0, 0, SCL1, 0, SCL1);
        accf[0][1] = __builtin_amdgcn_mfma_scale_f32_32x32x64_f8f6f4(a0, b1, accf[0][1], 0, 0, 0, SCL1, 0, SCL1);
        accf[1][0] = __builtin_amdgcn_mfma_scale_f32_32x32x64_f8f6f4(a1, b0, accf[1][0], 0, 0, 0, SCL1, 0, SCL1);
        accf[1][1] = __builtin_amdgcn_mfma_scale_f32_32x32x64_f8f6f4(a1, b1, accf[1][1], 0, 0, 0, SCL1, 0, SCL1);
    }

    // ---- fused epilogue: exp2( min( s*2C2 + nq_i + nq_j, 0 ) ) ----
    int rowBase = bi * 128 + wm * 64;
    int colBase = bj * 128 + wn * 64;
    float nqj[2] = { nq[colBase + ln31], nq[colBase + 32 + ln31] };

    float local = 0.f;
    if (bi != bj) {
#pragma unroll
        for (int mi = 0; mi < 2; ++mi) {
#pragma unroll
            for (int reg = 0; reg < 16; ++reg) {
                int rowf = (reg & 3) + 8 * (reg >> 2) + 4 * kh;
                float nqi = nq[rowBase + mi * 32 + rowf];
#pragma unroll
                for (int ni = 0; ni < 2; ++ni) {
                    float arg = fmaf(accf[mi][ni][reg], 2.f * C2, nqi + nqj[ni]);
                    local += __builtin_exp2f(fminf(arg, 0.f));
                }
            }
        }
    } else {
#pragma unroll
        for (int mi = 0; mi < 2; ++mi) {
#pragma unroll
            for (int reg = 0; reg < 16; ++reg) {
                int rowf = (reg & 3) + 8 * (reg >> 2) + 4 * kh;
                int gi = rowBase + mi * 32 + rowf;
                float nqi = nq[gi];
#pragma unroll
                for (int ni = 0; ni < 2; ++ni) {
                    int gj = colBase + ni * 32 + ln31;
                    float arg = fmaf(accf[mi][ni][reg], 2.f * C2, nqi + nqj[ni]);
                    float e = __builtin_exp2f(fminf(arg, 0.f));
                    local += (gi < gj) ? e : 0.f;
                }
            }
        }
    }

#pragma unroll
    for (int off = 32; off; off >>= 1) local += __shfl_down(local, off);
    if (lane == 0) wsum[wave] = local;
    __syncthreads();
    if (tid == 0) part[blockIdx.x] = wsum[0] + wsum[1] + wsum[2] + wsum[3];  // plain store
}

// Single small block: sum the 2080 partials, take the log.
__global__ __launch_bounds__(256) void reduce_kernel(const float* __restrict__ part,
                                                     float* __restrict__ out) {
    int tid = threadIdx.x;
    int wave = tid >> 6, lane = tid & 63;
    float s = 0.f;
    for (int i = tid; i < NBLK; i += 256) s += part[i];
#pragma unroll
    for (int off = 32; off; off >>= 1) s += __shfl_down(s, off);
    __shared__ float w[4];
    if (lane == 0) w[wave] = s;
    __syncthreads();
    if (tid == 0) {
        float total = 2.f * (w[0] + w[1] + w[2] + w[3]);
        out[0] = logf(total / ((float)NROWS * (float)(NROWS - 1)));
    }
}

extern "C" void kernel_launch(void* const* d_in, const int* in_sizes, int n_in,
                              void* d_out, int out_size, void* d_ws, size_t ws_size,
                              hipStream_t stream) {
    const float* z = (const float*)d_in[0];
    float* out = (float*)d_out;
    unsigned char* zb2 = (unsigned char*)d_ws;                    // 4 MB fp8, operand order
    float* nq = (float*)((char*)d_ws + (size_t)NROWS * KDIM);     // 32 KB
    float* part = nq + NROWS;                                     // 2080 floats

    prep_kernel<<<NROWS / 4, 256, 0, stream>>>(z, zb2, nq);
    gram_kernel<<<NBLK, 256, 0, stream>>>(zb2, nq, part);
    reduce_kernel<<<1, 256, 0, stream>>>(part, out);
}

// Round 12
// 83.519 us; speedup vs baseline: 3.8653x; 1.1143x over previous
//
#include <hip/hip_runtime.h>
#include <hip/hip_bf16.h>

#define NROWS 8192
#define KDIM  512
#define NT    64                 // 8192/128 tiles per dim
#define NBLK  (NT*(NT+1)/2)      // upper-triangle tile pairs = 2080
#define SCL1  0x7F7F7F7F         // E8M0 scale bytes = 2^0 = 1.0
#define STRIP4 8192              // 32 rows x 512 k x 0.5 B per strip
#define C2    0.0144269504f      // log2(e)/100

typedef __attribute__((ext_vector_type(16))) float f32x16;
typedef __attribute__((ext_vector_type(4))) int i32x4;
typedef __attribute__((ext_vector_type(8))) int i32x8;

__device__ __forceinline__ i32x8 mk_op4(i32x4 lo) {
    i32x8 r;
    r[0] = lo[0]; r[1] = lo[1]; r[2] = lo[2]; r[3] = lo[3];
    r[4] = 0; r[5] = 0; r[6] = 0; r[7] = 0;   // fp4 uses only first 4 dwords
    return r;
}

// nearest e2m1 (scale 1.0) code for |x|: {0,0.5,1,1.5,2,3,4,6}
__device__ __forceinline__ int fp4_code(float x) {
    float v = fabsf(x);
    int c = v < 0.25f ? 0 : v < 0.75f ? 1 : v < 1.25f ? 2 : v < 1.75f ? 3
          : v < 2.5f  ? 4 : v < 3.5f  ? 5 : v < 5.0f  ? 6 : 7;
    return c | (x < 0.f ? 8 : 0);
}

// z (fp32) -> fp4 e2m1 in MFMA-operand order (k-nibble order mirrors the
// HW-verified fp8 byte order; any consistent k-permutation is Gram-invariant):
//   zb4 addr = strip*8192 + kstep*1024 + seg*512 + (row&31)*16 + nibblepos
// nq[i] = -log2e/100 * ||z_i||^2 (exact fp32).
__global__ __launch_bounds__(256) void prep_kernel(const float* __restrict__ z,
                                                   unsigned char* __restrict__ zb4,
                                                   float* __restrict__ nq) {
    int wave = threadIdx.x >> 6, lane = threadIdx.x & 63;
    int row = blockIdx.x * 4 + wave;
    const float* zr = z + (size_t)row * KDIM + lane * 8;
    float4 v0 = *(const float4*)zr;
    float4 v1 = *(const float4*)(zr + 4);
    float vals[8] = {v0.x, v0.y, v0.z, v0.w, v1.x, v1.y, v1.z, v1.w};
    float s = 0.f;
    unsigned int pk = 0u;
#pragma unroll
    for (int i = 0; i < 8; ++i) {
        s += vals[i] * vals[i];
        pk |= (unsigned int)fp4_code(vals[i]) << (4 * i);   // nibble i = k0+i
    }
    int strip = row >> 5, lr = row & 31;
    size_t addr = (size_t)strip * STRIP4 + (lane >> 3) * 1024 +
                  ((lane >> 2) & 1) * 512 + lr * 16 + (lane & 3) * 4;
    *(unsigned int*)(zb4 + addr) = pk;
#pragma unroll
    for (int off = 32; off; off >>= 1) s += __shfl_down(s, off);
    if (lane == 0) nq[row] = -C2 * s;
}

// 128x128 Gram tile per block, 64x64 per wave (2x2 32x32x64 MX-fp4 MFMA).
// fp4 halves operand-return traffic vs fp8 (266 MB total) at identical MFMA
// count. Rolled K-loop, rotation decorrelates L2 bursts, 3 blocks/CU.
// No LDS staging, no barriers, no atomics.
__global__ __launch_bounds__(256, 3) void gram_kernel(const unsigned char* __restrict__ zb4,
                                                      const float* __restrict__ nq,
                                                      float* __restrict__ part) {
    __shared__ float wsum[4];

    int tid = threadIdx.x;
    int wave = tid >> 6, lane = tid & 63;
    int ln31 = lane & 31, kh = lane >> 5;
    int wm = wave >> 1, wn = wave & 1;

    // linear block id -> (bi, bj), bi <= bj
    int rem = blockIdx.x, bi = 0;
    while (rem >= NT - bi) { rem -= NT - bi; ++bi; }
    int bj = bi + rem;
    int rot = blockIdx.x & 7;

    int laneOff = kh * 512 + ln31 * 16;
    const unsigned char* pA0 = zb4 + (size_t)(bi * 4 + wm * 2) * STRIP4 + laneOff;
    const unsigned char* pA1 = pA0 + STRIP4;
    const unsigned char* pB0 = zb4 + (size_t)(bj * 4 + wn * 2) * STRIP4 + laneOff;
    const unsigned char* pB1 = pB0 + STRIP4;

    f32x16 accf[2][2];
#pragma unroll
    for (int mi = 0; mi < 2; ++mi)
#pragma unroll
        for (int ni = 0; ni < 2; ++ni)
#pragma unroll
            for (int r = 0; r < 16; ++r) accf[mi][ni][r] = 0.f;

#pragma unroll
    for (int ks = 0; ks < 8; ++ks) {
        int off = ((ks + rot) & 7) * 1024;   // rotated k-slice
        i32x8 a0 = mk_op4(*(const i32x4*)(pA0 + off));
        i32x8 a1 = mk_op4(*(const i32x4*)(pA1 + off));
        i32x8 b0 = mk_op4(*(const i32x4*)(pB0 + off));
        i32x8 b1 = mk_op4(*(const i32x4*)(pB1 + off));
        // cbsz=4 (A=fp4), blgp=4 (B=fp4), scales = 1.0
        accf[0][0] = __builtin_amdgcn_mfma_scale_f32_32x32x64_f8f6f4(a0, b0, accf[0][0], 4, 4, 0, SCL1, 0, SCL1);
        accf[0][1] = __builtin_amdgcn_mfma_scale_f32_32x32x64_f8f6f4(a0, b1, accf[0][1], 4, 4, 0, SCL1, 0, SCL1);
        accf[1][0] = __builtin_amdgcn_mfma_scale_f32_32x32x64_f8f6f4(a1, b0, accf[1][0], 4, 4, 0, SCL1, 0, SCL1);
        accf[1][1] = __builtin_amdgcn_mfma_scale_f32_32x32x64_f8f6f4(a1, b1, accf[1][1], 4, 4, 0, SCL1, 0, SCL1);
    }

    // ---- fused epilogue: exp2( min( s*2C2 + nq_i + nq_j, 0 ) ) ----
    int rowBase = bi * 128 + wm * 64;
    int colBase = bj * 128 + wn * 64;
    float nqj[2] = { nq[colBase + ln31], nq[colBase + 32 + ln31] };

    float local = 0.f;
    if (bi != bj) {
#pragma unroll
        for (int mi = 0; mi < 2; ++mi) {
#pragma unroll
            for (int reg = 0; reg < 16; ++reg) {
                int rowf = (reg & 3) + 8 * (reg >> 2) + 4 * kh;
                float nqi = nq[rowBase + mi * 32 + rowf];
#pragma unroll
                for (int ni = 0; ni < 2; ++ni) {
                    float arg = fmaf(accf[mi][ni][reg], 2.f * C2, nqi + nqj[ni]);
                    local += __builtin_exp2f(fminf(arg, 0.f));
                }
            }
        }
    } else {
#pragma unroll
        for (int mi = 0; mi < 2; ++mi) {
#pragma unroll
            for (int reg = 0; reg < 16; ++reg) {
                int rowf = (reg & 3) + 8 * (reg >> 2) + 4 * kh;
                int gi = rowBase + mi * 32 + rowf;
                float nqi = nq[gi];
#pragma unroll
                for (int ni = 0; ni < 2; ++ni) {
                    int gj = colBase + ni * 32 + ln31;
                    float arg = fmaf(accf[mi][ni][reg], 2.f * C2, nqi + nqj[ni]);
                    float e = __builtin_exp2f(fminf(arg, 0.f));
                    local += (gi < gj) ? e : 0.f;
                }
            }
        }
    }

#pragma unroll
    for (int off = 32; off; off >>= 1) local += __shfl_down(local, off);
    if (lane == 0) wsum[wave] = local;
    __syncthreads();
    if (tid == 0) part[blockIdx.x] = wsum[0] + wsum[1] + wsum[2] + wsum[3];  // plain store
}

// Single small block: sum the 2080 partials, take the log.
__global__ __launch_bounds__(256) void reduce_kernel(const float* __restrict__ part,
                                                     float* __restrict__ out) {
    int tid = threadIdx.x;
    int wave = tid >> 6, lane = tid & 63;
    float s = 0.f;
    for (int i = tid; i < NBLK; i += 256) s += part[i];
#pragma unroll
    for (int off = 32; off; off >>= 1) s += __shfl_down(s, off);
    __shared__ float w[4];
    if (lane == 0) w[wave] = s;
    __syncthreads();
    if (tid == 0) {
        float total = 2.f * (w[0] + w[1] + w[2] + w[3]);
        out[0] = logf(total / ((float)NROWS * (float)(NROWS - 1)));
    }
}

extern "C" void kernel_launch(void* const* d_in, const int* in_sizes, int n_in,
                              void* d_out, int out_size, void* d_ws, size_t ws_size,
                              hipStream_t stream) {
    const float* z = (const float*)d_in[0];
    float* out = (float*)d_out;
    unsigned char* zb4 = (unsigned char*)d_ws;                    // 2 MB fp4, operand order
    float* nq = (float*)((char*)d_ws + (size_t)NROWS * KDIM / 2); // 32 KB
    float* part = nq + NROWS;                                     // 2080 floats

    prep_kernel<<<NROWS / 4, 256, 0, stream>>>(z, zb4, nq);
    gram_kernel<<<NBLK, 256, 0, stream>>>(zb4, nq, part);
    reduce_kernel<<<1, 256, 0, stream>>>(part, out);
}